// Round 1
// baseline (306.365 us; speedup 1.0000x reference)
//
#include <hip/hip_runtime.h>

typedef short short4v __attribute__((ext_vector_type(4)));
typedef short short8v __attribute__((ext_vector_type(8)));
typedef float floatx4 __attribute__((ext_vector_type(4)));

#define SLEN 1024
#define DDIM 64
#define KSTR 72   // 64 + 8 pad (bf16 elems): keeps ds_read_b128 conflict-free, 16B-aligned

__device__ __forceinline__ unsigned short f2bf(float f) {
  union { float f; unsigned int u; } v; v.f = f;
  unsigned int u = v.u;
  u += 0x7fffu + ((u >> 16) & 1u);   // RNE
  return (unsigned short)(u >> 16);
}
__device__ __forceinline__ float bf2f(unsigned short h) {
  union { unsigned int u; float f; } v; v.u = ((unsigned int)h) << 16;
  return v.f;
}

// Flash attention fwd. Block = 256 thr (4 waves). Each block: 128 q-rows of one bh.
// Each wave: 32 q-rows (two 16-row MFMA row-sets sharing B fragments).
__global__ __launch_bounds__(256)
void attn_fwd(const float* __restrict__ Qg, const float* __restrict__ Kg,
              const float* __restrict__ Vg, const int* __restrict__ vraw,
              float* __restrict__ Og)
{
  __shared__ unsigned short K_lds[64 * KSTR];        // [key][d] natural
  __shared__ unsigned short VT_lds[64 * KSTR];       // [d][key] transposed
  __shared__ unsigned short P_lds[4][32 * KSTR];     // per-wave P round-trip

  const int t  = threadIdx.x;
  const int w  = t >> 6;        // wave id 0..3
  const int ln = t & 15;        // lane&15
  const int g  = (t >> 4) & 3;  // lane>>4 within wave

  const int q0 = blockIdx.x * 128;
  const int bh = blockIdx.y;

  // valid_lens: per-batch, b = bh/16. Defensive int64-vs-int32 detection:
  // int64 little-endian with values <2^31 => every odd int32 slot is 0.
  int vl;
  {
    const bool is64 = (vraw[1] == 0) && (vraw[3] == 0) && (vraw[5] == 0) && (vraw[7] == 0);
    const int b = bh >> 4;
    vl = is64 ? vraw[2 * b] : vraw[b];
  }

  // Preload Q fragments (A-operand layout: row=lane&15, k=(lane>>4)*8+j), bf16.
  short8v aq[2][2];
  #pragma unroll
  for (int m = 0; m < 2; ++m) {
    const float* qp = Qg + ((size_t)bh * SLEN + q0 + w * 32 + m * 16 + ln) * DDIM;
    #pragma unroll
    for (int st = 0; st < 2; ++st) {
      const int d0 = st * 32 + g * 8;
      const float4 f0 = *(const float4*)(qp + d0);
      const float4 f1 = *(const float4*)(qp + d0 + 4);
      short8v a;
      a[0] = (short)f2bf(f0.x); a[1] = (short)f2bf(f0.y);
      a[2] = (short)f2bf(f0.z); a[3] = (short)f2bf(f0.w);
      a[4] = (short)f2bf(f1.x); a[5] = (short)f2bf(f1.y);
      a[6] = (short)f2bf(f1.z); a[7] = (short)f2bf(f1.w);
      aq[m][st] = a;
    }
  }

  float mrow[2][4], lrow[2][4];
  floatx4 o[2][4];
  #pragma unroll
  for (int m = 0; m < 2; ++m) {
    #pragma unroll
    for (int i = 0; i < 4; ++i) { mrow[m][i] = -INFINITY; lrow[m][i] = 0.f; }
    #pragma unroll
    for (int f = 0; f < 4; ++f) o[m][f] = (floatx4){0.f, 0.f, 0.f, 0.f};
  }

  const float scale = 0.125f;   // 1/sqrt(64)

  for (int ch = 0; ch < SLEN / 64; ++ch) {
    const int k0 = ch * 64;
    __syncthreads();   // previous chunk's compute done before restaging

    // ---- stage K chunk [64 keys x 64 d], natural layout, fp32->bf16 ----
    {
      const int c4 = (t & 15) * 4;
      const int r0 = t >> 4;   // 0..15
      const float* kp = Kg + ((size_t)bh * SLEN + k0 + r0) * DDIM + c4;
      #pragma unroll
      for (int r = 0; r < 4; ++r) {
        const float4 v = *(const float4*)(kp + (size_t)(16 * r) * DDIM);
        short4v b;
        b[0] = (short)f2bf(v.x); b[1] = (short)f2bf(v.y);
        b[2] = (short)f2bf(v.z); b[3] = (short)f2bf(v.w);
        *(short4v*)&K_lds[(r0 + 16 * r) * KSTR + c4] = b;
      }
    }
    // ---- stage V chunk transposed: VT[d][key], 4x4 micro-tile per thread ----
    {
      const int kb = (t >> 4) * 4;   // key base
      const int db = (t & 15) * 4;   // d base
      const float* vp = Vg + ((size_t)bh * SLEN + k0 + kb) * DDIM + db;
      const float4 r0 = *(const float4*)(vp);
      const float4 r1 = *(const float4*)(vp + DDIM);
      const float4 r2 = *(const float4*)(vp + 2 * DDIM);
      const float4 r3 = *(const float4*)(vp + 3 * DDIM);
      short4v wa, wb, wc, wd;
      wa[0]=(short)f2bf(r0.x); wa[1]=(short)f2bf(r1.x); wa[2]=(short)f2bf(r2.x); wa[3]=(short)f2bf(r3.x);
      wb[0]=(short)f2bf(r0.y); wb[1]=(short)f2bf(r1.y); wb[2]=(short)f2bf(r2.y); wb[3]=(short)f2bf(r3.y);
      wc[0]=(short)f2bf(r0.z); wc[1]=(short)f2bf(r1.z); wc[2]=(short)f2bf(r2.z); wc[3]=(short)f2bf(r3.z);
      wd[0]=(short)f2bf(r0.w); wd[1]=(short)f2bf(r1.w); wd[2]=(short)f2bf(r2.w); wd[3]=(short)f2bf(r3.w);
      *(short4v*)&VT_lds[(db + 0) * KSTR + kb] = wa;
      *(short4v*)&VT_lds[(db + 1) * KSTR + kb] = wb;
      *(short4v*)&VT_lds[(db + 2) * KSTR + kb] = wc;
      *(short4v*)&VT_lds[(db + 3) * KSTR + kb] = wd;
    }
    __syncthreads();

    // ---- QK^T: S[q][key] for 32 q-rows x 64 keys ----
    floatx4 c[2][4];
    #pragma unroll
    for (int m = 0; m < 2; ++m)
      #pragma unroll
      for (int f = 0; f < 4; ++f) c[m][f] = (floatx4){0.f, 0.f, 0.f, 0.f};

    #pragma unroll
    for (int f = 0; f < 4; ++f) {
      // B operand: B[k=d][n=key] = K[key][d]; lane: n=ln, k=g*8+j(+32*st)
      const short8v b0 = *(const short8v*)&K_lds[(16 * f + ln) * KSTR + g * 8];
      const short8v b1 = *(const short8v*)&K_lds[(16 * f + ln) * KSTR + 32 + g * 8];
      #pragma unroll
      for (int m = 0; m < 2; ++m) {
        c[m][f] = __builtin_amdgcn_mfma_f32_16x16x32_bf16(aq[m][0], b0, c[m][f], 0, 0, 0);
        c[m][f] = __builtin_amdgcn_mfma_f32_16x16x32_bf16(aq[m][1], b1, c[m][f], 0, 0, 0);
      }
    }

    // ---- online softmax (C/D layout: row=g*4+i, col=ln+16f) ----
    #pragma unroll
    for (int m = 0; m < 2; ++m) {
      float s[4][4];
      #pragma unroll
      for (int f = 0; f < 4; ++f) {
        const int kg = k0 + 16 * f + ln;
        const bool valid = kg < vl;
        #pragma unroll
        for (int i = 0; i < 4; ++i)
          s[f][i] = valid ? c[m][f][i] * scale : 1e-6f;  // masked-fill, NOT -inf
      }
      #pragma unroll
      for (int i = 0; i < 4; ++i) {
        float r = fmaxf(fmaxf(s[0][i], s[1][i]), fmaxf(s[2][i], s[3][i]));
        r = fmaxf(r, __shfl_xor(r, 1));
        r = fmaxf(r, __shfl_xor(r, 2));
        r = fmaxf(r, __shfl_xor(r, 4));
        r = fmaxf(r, __shfl_xor(r, 8));
        const float mn = fmaxf(mrow[m][i], r);
        const float al = __expf(mrow[m][i] - mn);
        mrow[m][i] = mn;
        float rs = 0.f;
        #pragma unroll
        for (int f = 0; f < 4; ++f) {
          const unsigned short pb = f2bf(__expf(s[f][i] - mn));
          P_lds[w][(m * 16 + g * 4 + i) * KSTR + 16 * f + ln] = pb;
          rs += bf2f(pb);   // denominator matches bf16-rounded numerator weights
        }
        rs += __shfl_xor(rs, 1);
        rs += __shfl_xor(rs, 2);
        rs += __shfl_xor(rs, 4);
        rs += __shfl_xor(rs, 8);
        lrow[m][i] = lrow[m][i] * al + rs;
        #pragma unroll
        for (int f = 0; f < 4; ++f) o[m][f][i] *= al;
      }
    }

    // ---- PV: O += P * V  (P from LDS in A layout; V^T gives B layout b128) ----
    #pragma unroll
    for (int st = 0; st < 2; ++st) {
      const short8v ap0 = *(const short8v*)&P_lds[w][(ln)*KSTR + st * 32 + g * 8];
      const short8v ap1 = *(const short8v*)&P_lds[w][(16 + ln) * KSTR + st * 32 + g * 8];
      #pragma unroll
      for (int f = 0; f < 4; ++f) {
        const short8v bv = *(const short8v*)&VT_lds[(16 * f + ln) * KSTR + st * 32 + g * 8];
        o[0][f] = __builtin_amdgcn_mfma_f32_16x16x32_bf16(ap0, bv, o[0][f], 0, 0, 0);
        o[1][f] = __builtin_amdgcn_mfma_f32_16x16x32_bf16(ap1, bv, o[1][f], 0, 0, 0);
      }
    }
  }

  // ---- epilogue: O /= l, store fp32 ----
  #pragma unroll
  for (int m = 0; m < 2; ++m) {
    float inv[4];
    #pragma unroll
    for (int i = 0; i < 4; ++i) inv[i] = 1.0f / lrow[m][i];
    #pragma unroll
    for (int f = 0; f < 4; ++f) {
      #pragma unroll
      for (int i = 0; i < 4; ++i) {
        const size_t row = (size_t)bh * SLEN + q0 + w * 32 + m * 16 + g * 4 + i;
        Og[row * DDIM + 16 * f + ln] = o[m][f][i] * inv[i];
      }
    }
  }
}

extern "C" void kernel_launch(void* const* d_in, const int* in_sizes, int n_in,
                              void* d_out, int out_size, void* d_ws, size_t ws_size,
                              hipStream_t stream) {
  const float* Q = (const float*)d_in[0];
  const float* K = (const float*)d_in[1];
  const float* V = (const float*)d_in[2];
  const int*  vl = (const int*)d_in[3];
  float* out = (float*)d_out;
  dim3 grid(SLEN / 128, 128);   // 8 q-tiles x 128 batch-heads
  attn_fwd<<<grid, dim3(256), 0, stream>>>(Q, K, V, vl, out);
}

// Round 2
// 205.877 us; speedup vs baseline: 1.4881x; 1.4881x over previous
//
#include <hip/hip_runtime.h>

typedef short short4v __attribute__((ext_vector_type(4)));
typedef short short8v __attribute__((ext_vector_type(8)));
typedef float floatx4 __attribute__((ext_vector_type(4)));

#define SLEN 1024
#define DDIM 64
#define NBH  128
#define PSTR 72   // P_lds key-stride (64 + 8): b64 stores & b128 reads bank-optimal

__device__ __forceinline__ unsigned short f2bf(float f) {
  union { float f; unsigned int u; } v; v.f = f;
  unsigned int u = v.u;
  u += 0x7fffu + ((u >> 16) & 1u);   // RNE
  return (unsigned short)(u >> 16);
}
__device__ __forceinline__ float bf2f(unsigned short h) {
  union { unsigned int u; float f; } v; v.u = ((unsigned int)h) << 16;
  return v.f;
}

// ---------------- prepass: K fp32 -> bf16 swizzled tiles [bh][ch](64key x 64d) ----
// granule = 8 bf16 = 16 B; within a 64x128B tile, granule gr of row r stored at
// r*128 + (gr ^ (r&7))*16  -> all MFMA b128 fragment reads land 8 dwords/bank.
__global__ __launch_bounds__(256)
void prep_k(const float* __restrict__ Kg, unsigned short* __restrict__ wsK) {
  const int t = blockIdx.x * 256 + threadIdx.x;  // global granule id (1,048,576)
  const int tile = t >> 9;                       // 512 granules per tile
  const int q = t & 511;
  const int r = q >> 3, gr = q & 7;
  const float4 f0 = *(const float4*)(Kg + (size_t)t * 8);
  const float4 f1 = *(const float4*)(Kg + (size_t)t * 8 + 4);
  short8v s;
  s[0]=(short)f2bf(f0.x); s[1]=(short)f2bf(f0.y); s[2]=(short)f2bf(f0.z); s[3]=(short)f2bf(f0.w);
  s[4]=(short)f2bf(f1.x); s[5]=(short)f2bf(f1.y); s[6]=(short)f2bf(f1.z); s[7]=(short)f2bf(f1.w);
  *(short8v*)(wsK + (size_t)tile * 4096 + r * 64 + ((gr ^ (r & 7)) * 8)) = s;
}

// ---------------- prepass: V fp32 -> bf16 transposed swizzled tiles [bh][ch](64d x 64key)
__global__ __launch_bounds__(256)
void prep_v(const float* __restrict__ Vg, unsigned short* __restrict__ wsVT) {
  const int w = threadIdx.x >> 6;
  const int d = threadIdx.x & 63;
  const int tile = blockIdx.x * 4 + w;          // 2048 tiles (bh,ch)
  const int bh = tile >> 4, ch = tile & 15;
  const float* src = Vg + ((size_t)(bh * SLEN + ch * 64) * DDIM) + d;  // column d
  unsigned short* dst = wsVT + (size_t)tile * 4096 + d * 64;
  #pragma unroll
  for (int gg = 0; gg < 8; ++gg) {
    short8v s;
    #pragma unroll
    for (int j = 0; j < 8; ++j) s[j] = (short)f2bf(src[(size_t)(gg * 8 + j) * DDIM]);
    *(short8v*)(dst + ((gg ^ (d & 7)) * 8)) = s;
  }
}

// ---------------- main: flash attention, no-max softmax (mask fill = 1e-6 => safe) ----
__global__ __launch_bounds__(256)
void attn_main(const float* __restrict__ Qg, const unsigned short* __restrict__ wsK,
               const unsigned short* __restrict__ wsVT, const int* __restrict__ vraw,
               float* __restrict__ Og)
{
  __shared__ unsigned short K_lds[4096];        // 64x64 bf16, swizzled, 8 KB
  __shared__ unsigned short VT_lds[4096];       // 64x64 bf16, swizzled, 8 KB
  __shared__ unsigned short P_lds[4][32 * PSTR];// per-wave P^T: [q][key]
  __shared__ float l_lds[4][32];

  const int t  = threadIdx.x;
  const int w  = t >> 6;
  const int ln = t & 15;
  const int g  = (t >> 4) & 3;
  const int q0 = blockIdx.x * 128;
  const int bh = blockIdx.y;

  int vl;
  {
    const bool is64 = (vraw[1] == 0) && (vraw[3] == 0) && (vraw[5] == 0) && (vraw[7] == 0);
    const int b = bh >> 4;
    vl = is64 ? vraw[2 * b] : vraw[b];
  }

  // Q as B-operand fragments (B[k=d][n=q]: n=lane&15, k=g*8+j), pre-scaled by
  // (1/sqrt(64))*log2(e) so softmax is a bare v_exp_f32 (2^x) on the MFMA output.
  const float qs = 0.125f * 1.44269504f;
  short8v bq[2][2];
  #pragma unroll
  for (int nt = 0; nt < 2; ++nt) {
    const float* qp = Qg + ((size_t)bh * SLEN + q0 + w * 32 + nt * 16 + ln) * DDIM;
    #pragma unroll
    for (int st = 0; st < 2; ++st) {
      const float4 f0 = *(const float4*)(qp + st * 32 + g * 8);
      const float4 f1 = *(const float4*)(qp + st * 32 + g * 8 + 4);
      short8v a;
      a[0]=(short)f2bf(f0.x*qs); a[1]=(short)f2bf(f0.y*qs);
      a[2]=(short)f2bf(f0.z*qs); a[3]=(short)f2bf(f0.w*qs);
      a[4]=(short)f2bf(f1.x*qs); a[5]=(short)f2bf(f1.y*qs);
      a[6]=(short)f2bf(f1.z*qs); a[7]=(short)f2bf(f1.w*qs);
      bq[nt][st] = a;
    }
  }

  const int l7  = ln & 7;
  const int sw0 = ((g) ^ l7) * 8;        // swizzled granule offset, st=0
  const int sw1 = ((4 + g) ^ l7) * 8;    // st=1

  floatx4 o[2][4];
  #pragma unroll
  for (int m = 0; m < 2; ++m)
    #pragma unroll
    for (int f = 0; f < 4; ++f) o[m][f] = (floatx4){0.f, 0.f, 0.f, 0.f};
  float l0 = 0.f, l1 = 0.f;

  for (int ch = 0; ch < 16; ++ch) {
    __syncthreads();   // previous chunk's LDS reads done
    {
      const size_t toff = ((size_t)bh * 16 + ch) * 4096;
      const short8v* gk = (const short8v*)(wsK + toff);
      const short8v* gv = (const short8v*)(wsVT + toff);
      short8v* lk = (short8v*)K_lds;
      short8v* lv = (short8v*)VT_lds;
      lk[t]       = gk[t];
      lk[t + 256] = gk[t + 256];
      lv[t]       = gv[t];
      lv[t + 256] = gv[t + 256];
    }
    __syncthreads();

    // ---- S^T = K * Q^T : c[mt][nt], lane reg i holds key = mt*16+g*4+i, q = nt*16+ln
    floatx4 c[4][2];
    #pragma unroll
    for (int mt = 0; mt < 4; ++mt) {
      const short8v a0 = *(const short8v*)&K_lds[(mt * 16 + ln) * 64 + sw0];
      const short8v a1 = *(const short8v*)&K_lds[(mt * 16 + ln) * 64 + sw1];
      #pragma unroll
      for (int nt = 0; nt < 2; ++nt) {
        floatx4 acc = (floatx4){0.f, 0.f, 0.f, 0.f};
        acc = __builtin_amdgcn_mfma_f32_16x16x32_bf16(a0, bq[nt][0], acc, 0, 0, 0);
        acc = __builtin_amdgcn_mfma_f32_16x16x32_bf16(a1, bq[nt][1], acc, 0, 0, 0);
        c[mt][nt] = acc;
      }
    }

    // ---- p = exp2(s) (masked -> 1.0), pack 4 consecutive keys per b64 store ----
    float rs0 = 0.f, rs1 = 0.f;
    #pragma unroll
    for (int mt = 0; mt < 4; ++mt) {
      const int kg = ch * 64 + mt * 16 + g * 4;
      #pragma unroll
      for (int nt = 0; nt < 2; ++nt) {
        unsigned short h[4];
        float pr = 0.f;
        #pragma unroll
        for (int i = 0; i < 4; ++i) {
          const float p = (kg + i < vl) ? __builtin_amdgcn_exp2f(c[mt][nt][i]) : 1.0f;
          const unsigned short hb = f2bf(p);
          h[i] = hb;
          pr += bf2f(hb);   // denominator matches bf16-rounded numerator
        }
        if (nt == 0) rs0 += pr; else rs1 += pr;
        short4v pv; pv[0]=(short)h[0]; pv[1]=(short)h[1]; pv[2]=(short)h[2]; pv[3]=(short)h[3];
        *(short4v*)&P_lds[w][(nt * 16 + ln) * PSTR + mt * 16 + g * 4] = pv;
      }
    }
    rs0 += __shfl_xor(rs0, 16); rs0 += __shfl_xor(rs0, 32);
    rs1 += __shfl_xor(rs1, 16); rs1 += __shfl_xor(rs1, 32);
    l0 += rs0; l1 += rs1;

    // ---- O += P * V ----
    #pragma unroll
    for (int st = 0; st < 2; ++st) {
      const short8v ap0 = *(const short8v*)&P_lds[w][(ln)      * PSTR + st * 32 + g * 8];
      const short8v ap1 = *(const short8v*)&P_lds[w][(16 + ln) * PSTR + st * 32 + g * 8];
      const int sw = (st == 0) ? sw0 : sw1;
      #pragma unroll
      for (int f = 0; f < 4; ++f) {
        const short8v bv = *(const short8v*)&VT_lds[(f * 16 + ln) * 64 + sw];
        o[0][f] = __builtin_amdgcn_mfma_f32_16x16x32_bf16(ap0, bv, o[0][f], 0, 0, 0);
        o[1][f] = __builtin_amdgcn_mfma_f32_16x16x32_bf16(ap1, bv, o[1][f], 0, 0, 0);
      }
    }
  }

  // ---- epilogue: O /= l (l lives at q=ln+16nt; O rows at q=g*4+i+16mt -> via LDS) ----
  if (g == 0) { l_lds[w][ln] = l0; l_lds[w][16 + ln] = l1; }
  #pragma unroll
  for (int mt2 = 0; mt2 < 2; ++mt2) {
    #pragma unroll
    for (int i = 0; i < 4; ++i) {
      const float inv = 1.0f / l_lds[w][mt2 * 16 + g * 4 + i];
      const size_t row = (size_t)bh * SLEN + q0 + w * 32 + mt2 * 16 + g * 4 + i;
      #pragma unroll
      for (int f = 0; f < 4; ++f)
        Og[row * DDIM + f * 16 + ln] = o[mt2][f][i] * inv;
    }
  }
}

// ================= fallback (round-1 kernel, used only if ws too small) =================
#define KSTR 72
__global__ __launch_bounds__(256)
void attn_fwd_fallback(const float* __restrict__ Qg, const float* __restrict__ Kg,
                       const float* __restrict__ Vg, const int* __restrict__ vraw,
                       float* __restrict__ Og)
{
  __shared__ unsigned short K_lds[64 * KSTR];
  __shared__ unsigned short VT_lds[64 * KSTR];
  __shared__ unsigned short P_lds[4][32 * KSTR];
  const int t  = threadIdx.x;
  const int w  = t >> 6;
  const int ln = t & 15;
  const int g  = (t >> 4) & 3;
  const int q0 = blockIdx.x * 128;
  const int bh = blockIdx.y;
  int vl;
  {
    const bool is64 = (vraw[1] == 0) && (vraw[3] == 0) && (vraw[5] == 0) && (vraw[7] == 0);
    const int b = bh >> 4;
    vl = is64 ? vraw[2 * b] : vraw[b];
  }
  short8v aq[2][2];
  #pragma unroll
  for (int m = 0; m < 2; ++m) {
    const float* qp = Qg + ((size_t)bh * SLEN + q0 + w * 32 + m * 16 + ln) * DDIM;
    #pragma unroll
    for (int st = 0; st < 2; ++st) {
      const int d0 = st * 32 + g * 8;
      const float4 f0 = *(const float4*)(qp + d0);
      const float4 f1 = *(const float4*)(qp + d0 + 4);
      short8v a;
      a[0]=(short)f2bf(f0.x); a[1]=(short)f2bf(f0.y); a[2]=(short)f2bf(f0.z); a[3]=(short)f2bf(f0.w);
      a[4]=(short)f2bf(f1.x); a[5]=(short)f2bf(f1.y); a[6]=(short)f2bf(f1.z); a[7]=(short)f2bf(f1.w);
      aq[m][st] = a;
    }
  }
  float mrow[2][4], lrow[2][4];
  floatx4 o[2][4];
  #pragma unroll
  for (int m = 0; m < 2; ++m) {
    #pragma unroll
    for (int i = 0; i < 4; ++i) { mrow[m][i] = -INFINITY; lrow[m][i] = 0.f; }
    #pragma unroll
    for (int f = 0; f < 4; ++f) o[m][f] = (floatx4){0.f, 0.f, 0.f, 0.f};
  }
  const float scale = 0.125f;
  for (int ch = 0; ch < SLEN / 64; ++ch) {
    const int k0 = ch * 64;
    __syncthreads();
    {
      const int c4 = (t & 15) * 4;
      const int r0 = t >> 4;
      const float* kp = Kg + ((size_t)bh * SLEN + k0 + r0) * DDIM + c4;
      #pragma unroll
      for (int r = 0; r < 4; ++r) {
        const float4 v = *(const float4*)(kp + (size_t)(16 * r) * DDIM);
        short4v b;
        b[0]=(short)f2bf(v.x); b[1]=(short)f2bf(v.y); b[2]=(short)f2bf(v.z); b[3]=(short)f2bf(v.w);
        *(short4v*)&K_lds[(r0 + 16 * r) * KSTR + c4] = b;
      }
    }
    {
      const int kb = (t >> 4) * 4;
      const int db = (t & 15) * 4;
      const float* vp = Vg + ((size_t)bh * SLEN + k0 + kb) * DDIM + db;
      const float4 r0 = *(const float4*)(vp);
      const float4 r1 = *(const float4*)(vp + DDIM);
      const float4 r2 = *(const float4*)(vp + 2 * DDIM);
      const float4 r3 = *(const float4*)(vp + 3 * DDIM);
      short4v wa, wb, wc, wd;
      wa[0]=(short)f2bf(r0.x); wa[1]=(short)f2bf(r1.x); wa[2]=(short)f2bf(r2.x); wa[3]=(short)f2bf(r3.x);
      wb[0]=(short)f2bf(r0.y); wb[1]=(short)f2bf(r1.y); wb[2]=(short)f2bf(r2.y); wb[3]=(short)f2bf(r3.y);
      wc[0]=(short)f2bf(r0.z); wc[1]=(short)f2bf(r1.z); wc[2]=(short)f2bf(r2.z); wc[3]=(short)f2bf(r3.z);
      wd[0]=(short)f2bf(r0.w); wd[1]=(short)f2bf(r1.w); wd[2]=(short)f2bf(r2.w); wd[3]=(short)f2bf(r3.w);
      *(short4v*)&VT_lds[(db + 0) * KSTR + kb] = wa;
      *(short4v*)&VT_lds[(db + 1) * KSTR + kb] = wb;
      *(short4v*)&VT_lds[(db + 2) * KSTR + kb] = wc;
      *(short4v*)&VT_lds[(db + 3) * KSTR + kb] = wd;
    }
    __syncthreads();
    floatx4 c[2][4];
    #pragma unroll
    for (int m = 0; m < 2; ++m)
      #pragma unroll
      for (int f = 0; f < 4; ++f) c[m][f] = (floatx4){0.f, 0.f, 0.f, 0.f};
    #pragma unroll
    for (int f = 0; f < 4; ++f) {
      const short8v b0 = *(const short8v*)&K_lds[(16 * f + ln) * KSTR + g * 8];
      const short8v b1 = *(const short8v*)&K_lds[(16 * f + ln) * KSTR + 32 + g * 8];
      #pragma unroll
      for (int m = 0; m < 2; ++m) {
        c[m][f] = __builtin_amdgcn_mfma_f32_16x16x32_bf16(aq[m][0], b0, c[m][f], 0, 0, 0);
        c[m][f] = __builtin_amdgcn_mfma_f32_16x16x32_bf16(aq[m][1], b1, c[m][f], 0, 0, 0);
      }
    }
    #pragma unroll
    for (int m = 0; m < 2; ++m) {
      float s[4][4];
      #pragma unroll
      for (int f = 0; f < 4; ++f) {
        const int kgl = k0 + 16 * f + ln;
        const bool valid = kgl < vl;
        #pragma unroll
        for (int i = 0; i < 4; ++i)
          s[f][i] = valid ? c[m][f][i] * scale : 1e-6f;
      }
      #pragma unroll
      for (int i = 0; i < 4; ++i) {
        float r = fmaxf(fmaxf(s[0][i], s[1][i]), fmaxf(s[2][i], s[3][i]));
        r = fmaxf(r, __shfl_xor(r, 1));
        r = fmaxf(r, __shfl_xor(r, 2));
        r = fmaxf(r, __shfl_xor(r, 4));
        r = fmaxf(r, __shfl_xor(r, 8));
        const float mn = fmaxf(mrow[m][i], r);
        const float al = __expf(mrow[m][i] - mn);
        mrow[m][i] = mn;
        float rs = 0.f;
        #pragma unroll
        for (int f = 0; f < 4; ++f) {
          const unsigned short pb = f2bf(__expf(s[f][i] - mn));
          P_lds[w][(m * 16 + g * 4 + i) * KSTR + 16 * f + ln] = pb;
          rs += bf2f(pb);
        }
        rs += __shfl_xor(rs, 1);
        rs += __shfl_xor(rs, 2);
        rs += __shfl_xor(rs, 4);
        rs += __shfl_xor(rs, 8);
        lrow[m][i] = lrow[m][i] * al + rs;
        #pragma unroll
        for (int f = 0; f < 4; ++f) o[m][f][i] *= al;
      }
    }
    #pragma unroll
    for (int st = 0; st < 2; ++st) {
      const short8v ap0 = *(const short8v*)&P_lds[w][(ln)*KSTR + st * 32 + g * 8];
      const short8v ap1 = *(const short8v*)&P_lds[w][(16 + ln) * KSTR + st * 32 + g * 8];
      #pragma unroll
      for (int f = 0; f < 4; ++f) {
        const short8v bv = *(const short8v*)&VT_lds[(16 * f + ln) * KSTR + st * 32 + g * 8];
        o[0][f] = __builtin_amdgcn_mfma_f32_16x16x32_bf16(ap0, bv, o[0][f], 0, 0, 0);
        o[1][f] = __builtin_amdgcn_mfma_f32_16x16x32_bf16(ap1, bv, o[1][f], 0, 0, 0);
      }
    }
  }
  #pragma unroll
  for (int m = 0; m < 2; ++m) {
    float inv[4];
    #pragma unroll
    for (int i = 0; i < 4; ++i) inv[i] = 1.0f / lrow[m][i];
    #pragma unroll
    for (int f = 0; f < 4; ++f) {
      #pragma unroll
      for (int i = 0; i < 4; ++i) {
        const size_t row = (size_t)bh * SLEN + q0 + w * 32 + m * 16 + g * 4 + i;
        Og[row * DDIM + 16 * f + ln] = o[m][f][i] * inv[i];
      }
    }
  }
}

extern "C" void kernel_launch(void* const* d_in, const int* in_sizes, int n_in,
                              void* d_out, int out_size, void* d_ws, size_t ws_size,
                              hipStream_t stream) {
  const float* Q = (const float*)d_in[0];
  const float* K = (const float*)d_in[1];
  const float* V = (const float*)d_in[2];
  const int*  vl = (const int*)d_in[3];
  float* out = (float*)d_out;

  const size_t ws_need = (size_t)2 * NBH * SLEN * DDIM * 2;  // 33,554,432 B
  if (ws_size >= ws_need) {
    unsigned short* wsK  = (unsigned short*)d_ws;
    unsigned short* wsVT = wsK + (size_t)NBH * SLEN * DDIM;
    prep_k<<<4096, 256, 0, stream>>>(K, wsK);
    prep_v<<<512, 256, 0, stream>>>(V, wsVT);
    attn_main<<<dim3(SLEN / 128, NBH), dim3(256), 0, stream>>>(Q, wsK, wsVT, vl, out);
  } else {
    attn_fwd_fallback<<<dim3(SLEN / 128, NBH), dim3(256), 0, stream>>>(Q, K, V, vl, out);
  }
}

// Round 3
// 175.105 us; speedup vs baseline: 1.7496x; 1.1757x over previous
//
#include <hip/hip_runtime.h>
#include <hip/hip_bf16.h>

typedef short short4v __attribute__((ext_vector_type(4)));
typedef short short8v __attribute__((ext_vector_type(8)));
typedef float floatx4 __attribute__((ext_vector_type(4)));

#define SLEN 1024
#define DDIM 64
#define NBH  128
#define PSTR 72   // P_lds key-stride (64 + 8): b64 stores & b128 reads bank-optimal

__device__ __forceinline__ unsigned short f2bf(float f) {
  union { float f; unsigned int u; } v; v.f = f;
  unsigned int u = v.u;
  u += 0x7fffu + ((u >> 16) & 1u);   // RNE
  return (unsigned short)(u >> 16);
}

// packed fp32x2 -> bf16x2 (RNE); low short = first arg
__device__ __forceinline__ unsigned int pkbf(float a, float b) {
  __hip_bfloat162 h = __float22bfloat162_rn(float2{a, b});
  union { __hip_bfloat162 h; unsigned int u; } c; c.h = h;
  return c.u;
}

// async global->LDS DMA, 16B per lane; LDS dest = wave-uniform base + lane*16
__device__ __forceinline__ void ld_lds16(const void* g, void* l) {
  __builtin_amdgcn_global_load_lds(
      (const __attribute__((address_space(1))) void*)g,
      (__attribute__((address_space(3))) void*)l, 16, 0, 0);
}

// ---------------- prepass: K fp32 -> bf16 swizzled tiles [bh][ch](64key x 64d) ----
// granule = 8 bf16 = 16 B; granule gr of row r stored at r*128B + ((gr^(r&7))*16)B.
__global__ __launch_bounds__(256)
void prep_k(const float* __restrict__ Kg, unsigned short* __restrict__ wsK) {
  const int t = blockIdx.x * 256 + threadIdx.x;  // global granule id (1,048,576)
  const int tile = t >> 9;
  const int q = t & 511;
  const int r = q >> 3, gr = q & 7;
  const float4 f0 = *(const float4*)(Kg + (size_t)t * 8);
  const float4 f1 = *(const float4*)(Kg + (size_t)t * 8 + 4);
  short8v s;
  s[0]=(short)f2bf(f0.x); s[1]=(short)f2bf(f0.y); s[2]=(short)f2bf(f0.z); s[3]=(short)f2bf(f0.w);
  s[4]=(short)f2bf(f1.x); s[5]=(short)f2bf(f1.y); s[6]=(short)f2bf(f1.z); s[7]=(short)f2bf(f1.w);
  *(short8v*)(wsK + (size_t)tile * 4096 + r * 64 + ((gr ^ (r & 7)) * 8)) = s;
}

// -------- prepass: V fp32 -> bf16 transposed swizzled tiles + per-chunk col sums ----
__global__ __launch_bounds__(256)
void prep_v(const float* __restrict__ Vg, unsigned short* __restrict__ wsVT,
            float* __restrict__ CS) {
  const int w = threadIdx.x >> 6;
  const int d = threadIdx.x & 63;
  const int tile = blockIdx.x * 4 + w;          // 2048 tiles (bh,ch)
  const int bh = tile >> 4, ch = tile & 15;
  const float* src = Vg + ((size_t)(bh * SLEN + ch * 64) * DDIM) + d;  // column d
  unsigned short* dst = wsVT + (size_t)tile * 4096 + d * 64;
  float sum = 0.f;
  #pragma unroll
  for (int gg = 0; gg < 8; ++gg) {
    short8v s;
    #pragma unroll
    for (int j = 0; j < 8; ++j) {
      const float x = src[(size_t)(gg * 8 + j) * DDIM];
      sum += x;
      s[j] = (short)f2bf(x);
    }
    *(short8v*)(dst + ((gg ^ (d & 7)) * 8)) = s;
  }
  if (CS) CS[(size_t)tile * 64 + d] = sum;
}

// -------- prepass: per-chunk col sums -> suffix sums in place (SV[ch] = sum ch..15) ----
__global__ __launch_bounds__(64)
void prep_sv(float* __restrict__ CS) {
  const int bh = blockIdx.x;
  const int d  = threadIdx.x;
  float acc = 0.f;
  for (int ch = 15; ch >= 0; --ch) {
    const size_t idx = ((size_t)bh * 16 + ch) * 64 + d;
    acc += CS[idx];
    CS[idx] = acc;
  }
}

// ---------------- main: flash attention, no-max softmax (mask fill = 1e-6 => safe) ----
__global__ __launch_bounds__(256)
void attn_main(const float* __restrict__ Qg, const unsigned short* __restrict__ wsK,
               const unsigned short* __restrict__ wsVT, const float* __restrict__ SV,
               const int* __restrict__ vraw, float* __restrict__ Og)
{
  __shared__ unsigned short K_lds[2][4096];     // 64x64 bf16 swizzled, double-buffered
  __shared__ unsigned short VT_lds[2][4096];
  __shared__ unsigned short P_lds[4][32 * PSTR];// per-wave P^T: [q][key]

  const int t  = threadIdx.x;
  const int w  = t >> 6;
  const int ln = t & 15;
  const int g  = (t >> 4) & 3;
  const int q0 = blockIdx.x * 128;
  const int bh = blockIdx.y;

  int vl;
  {
    const bool is64 = (vraw[1] == 0) && (vraw[3] == 0) && (vraw[5] == 0) && (vraw[7] == 0);
    const int b = bh >> 4;
    vl = is64 ? vraw[2 * b] : vraw[b];
  }
  const int full_ch     = vl >> 6;                 // chunks with all keys valid
  const int has_partial = (vl & 63) ? 1 : 0;
  const int nch         = SV ? (full_ch + has_partial) : 16;
  const int tail_start  = full_ch + has_partial;   // first fully-masked chunk

  // Q as B-operand fragments, pre-scaled by (1/8)*log2(e) so softmax = exp2.
  const float qs = 0.125f * 1.44269504f;
  short8v bq[2][2];
  #pragma unroll
  for (int nt = 0; nt < 2; ++nt) {
    const float* qp = Qg + ((size_t)bh * SLEN + q0 + w * 32 + nt * 16 + ln) * DDIM;
    #pragma unroll
    for (int st = 0; st < 2; ++st) {
      const float4 f0 = *(const float4*)(qp + st * 32 + g * 8);
      const float4 f1 = *(const float4*)(qp + st * 32 + g * 8 + 4);
      short8v a;
      a[0]=(short)f2bf(f0.x*qs); a[1]=(short)f2bf(f0.y*qs);
      a[2]=(short)f2bf(f0.z*qs); a[3]=(short)f2bf(f0.w*qs);
      a[4]=(short)f2bf(f1.x*qs); a[5]=(short)f2bf(f1.y*qs);
      a[6]=(short)f2bf(f1.z*qs); a[7]=(short)f2bf(f1.w*qs);
      bq[nt][st] = a;
    }
  }

  const int l7  = ln & 7;
  const int sw0 = ((g) ^ l7) * 8;
  const int sw1 = ((4 + g) ^ l7) * 8;

  short8v ones;   // bf16 1.0 x8 : B-operand for row-sum MFMA
  #pragma unroll
  for (int j = 0; j < 8; ++j) ones[j] = (short)0x3F80;

  floatx4 o[2][4], lacc[2];
  #pragma unroll
  for (int m = 0; m < 2; ++m) {
    lacc[m] = (floatx4){0.f, 0.f, 0.f, 0.f};
    #pragma unroll
    for (int f = 0; f < 4; ++f) o[m][f] = (floatx4){0.f, 0.f, 0.f, 0.f};
  }

  const size_t tbase = (size_t)bh * 16 * 4096;
  auto issue = [&](int ch, int b) {
    const unsigned short* gk = wsK  + tbase + (size_t)ch * 4096;
    const unsigned short* gv = wsVT + tbase + (size_t)ch * 4096;
    ld_lds16(gk + (size_t)t * 8,         &K_lds[b][t * 8]);
    ld_lds16(gk + (size_t)(t + 256) * 8, &K_lds[b][(t + 256) * 8]);
    ld_lds16(gv + (size_t)t * 8,         &VT_lds[b][t * 8]);
    ld_lds16(gv + (size_t)(t + 256) * 8, &VT_lds[b][(t + 256) * 8]);
  };

  if (nch > 0) issue(0, 0);

  for (int ch = 0; ch < nch; ++ch) {
    const int b = ch & 1;
    if (ch + 1 < nch) {
      issue(ch + 1, b ^ 1);                    // prefetch next chunk (other buffer)
      __builtin_amdgcn_s_waitcnt(0x0f74);      // vmcnt(4): this chunk's 4 DMAs landed
    } else {
      __builtin_amdgcn_s_waitcnt(0x0f70);      // vmcnt(0)
    }
    __builtin_amdgcn_s_barrier();              // all waves' chunk-ch DMA landed

    // ---- S^T = K * Q^T : lane reg i holds key = mt*16+g*4+i, q = nt*16+ln ----
    floatx4 c[4][2];
    #pragma unroll
    for (int mt = 0; mt < 4; ++mt) {
      const short8v a0 = *(const short8v*)&K_lds[b][(mt * 16 + ln) * 64 + sw0];
      const short8v a1 = *(const short8v*)&K_lds[b][(mt * 16 + ln) * 64 + sw1];
      #pragma unroll
      for (int nt = 0; nt < 2; ++nt) {
        floatx4 acc = (floatx4){0.f, 0.f, 0.f, 0.f};
        acc = __builtin_amdgcn_mfma_f32_16x16x32_bf16(a0, bq[nt][0], acc, 0, 0, 0);
        acc = __builtin_amdgcn_mfma_f32_16x16x32_bf16(a1, bq[nt][1], acc, 0, 0, 0);
        c[mt][nt] = acc;
      }
    }

    // ---- p = exp2(s) (masked -> exp2(0) = 1.0), packed cvt, b64 stores ----
    const bool fullv = (ch < full_ch);
    #pragma unroll
    for (int mt = 0; mt < 4; ++mt) {
      const int kg = ch * 64 + mt * 16 + g * 4;
      #pragma unroll
      for (int nt = 0; nt < 2; ++nt) {
        float p[4];
        if (fullv) {
          #pragma unroll
          for (int i = 0; i < 4; ++i) p[i] = __builtin_amdgcn_exp2f(c[mt][nt][i]);
        } else {
          #pragma unroll
          for (int i = 0; i < 4; ++i) {
            const float x = (kg + i < vl) ? c[mt][nt][i] : 0.0f;
            p[i] = __builtin_amdgcn_exp2f(x);
          }
        }
        union { short4v v; unsigned int u[2]; } pk;
        pk.u[0] = pkbf(p[0], p[1]);
        pk.u[1] = pkbf(p[2], p[3]);
        *(short4v*)&P_lds[w][(nt * 16 + ln) * PSTR + mt * 16 + g * 4] = pk.v;
      }
    }

    // ---- O += P*V ; l += P*ones (row-sum in C-layout, matches O rows) ----
    #pragma unroll
    for (int st = 0; st < 2; ++st) {
      const short8v ap0 = *(const short8v*)&P_lds[w][(ln)      * PSTR + st * 32 + g * 8];
      const short8v ap1 = *(const short8v*)&P_lds[w][(16 + ln) * PSTR + st * 32 + g * 8];
      lacc[0] = __builtin_amdgcn_mfma_f32_16x16x32_bf16(ap0, ones, lacc[0], 0, 0, 0);
      lacc[1] = __builtin_amdgcn_mfma_f32_16x16x32_bf16(ap1, ones, lacc[1], 0, 0, 0);
      const int sw = (st == 0) ? sw0 : sw1;
      #pragma unroll
      for (int f = 0; f < 4; ++f) {
        const short8v bv = *(const short8v*)&VT_lds[b][(f * 16 + ln) * 64 + sw];
        o[0][f] = __builtin_amdgcn_mfma_f32_16x16x32_bf16(ap0, bv, o[0][f], 0, 0, 0);
        o[1][f] = __builtin_amdgcn_mfma_f32_16x16x32_bf16(ap1, bv, o[1][f], 0, 0, 0);
      }
    }

    if (ch + 1 < nch) __builtin_amdgcn_s_barrier();  // reads of buf b done before reuse
  }

  // ---- fully-masked tail: O += suffix colsum of V, l += #masked (p = 1.0 each) ----
  if (SV != nullptr && tail_start < 16) {
    const float* sv = SV + ((size_t)bh * 16 + tail_start) * 64;
    float svf[4];
    #pragma unroll
    for (int f = 0; f < 4; ++f) svf[f] = sv[f * 16 + ln];
    const float ml = (float)(SLEN - tail_start * 64);
    #pragma unroll
    for (int m = 0; m < 2; ++m) {
      #pragma unroll
      for (int i = 0; i < 4; ++i) lacc[m][i] += ml;
      #pragma unroll
      for (int f = 0; f < 4; ++f)
        #pragma unroll
        for (int i = 0; i < 4; ++i) o[m][f][i] += svf[f];
    }
  }

  // ---- epilogue: O /= l (lacc is in C-layout: same rows as O, no LDS needed) ----
  #pragma unroll
  for (int m = 0; m < 2; ++m) {
    #pragma unroll
    for (int i = 0; i < 4; ++i) {
      const float inv = 1.0f / lacc[m][i];
      const size_t row = (size_t)bh * SLEN + q0 + w * 32 + m * 16 + g * 4 + i;
      #pragma unroll
      for (int f = 0; f < 4; ++f)
        Og[row * DDIM + f * 16 + ln] = o[m][f][i] * inv;
    }
  }
}

// ================= fallback (round-1 kernel, used only if ws too small) =================
#define KSTR 72
__device__ __forceinline__ float bf2f(unsigned short h) {
  union { unsigned int u; float f; } v; v.u = ((unsigned int)h) << 16;
  return v.f;
}
__global__ __launch_bounds__(256)
void attn_fwd_fallback(const float* __restrict__ Qg, const float* __restrict__ Kg,
                       const float* __restrict__ Vg, const int* __restrict__ vraw,
                       float* __restrict__ Og)
{
  __shared__ unsigned short K_lds[64 * KSTR];
  __shared__ unsigned short VT_lds[64 * KSTR];
  __shared__ unsigned short P_lds[4][32 * KSTR];
  const int t  = threadIdx.x;
  const int w  = t >> 6;
  const int ln = t & 15;
  const int g  = (t >> 4) & 3;
  const int q0 = blockIdx.x * 128;
  const int bh = blockIdx.y;
  int vl;
  {
    const bool is64 = (vraw[1] == 0) && (vraw[3] == 0) && (vraw[5] == 0) && (vraw[7] == 0);
    const int b = bh >> 4;
    vl = is64 ? vraw[2 * b] : vraw[b];
  }
  short8v aq[2][2];
  #pragma unroll
  for (int m = 0; m < 2; ++m) {
    const float* qp = Qg + ((size_t)bh * SLEN + q0 + w * 32 + m * 16 + ln) * DDIM;
    #pragma unroll
    for (int st = 0; st < 2; ++st) {
      const int d0 = st * 32 + g * 8;
      const float4 f0 = *(const float4*)(qp + d0);
      const float4 f1 = *(const float4*)(qp + d0 + 4);
      short8v a;
      a[0]=(short)f2bf(f0.x); a[1]=(short)f2bf(f0.y); a[2]=(short)f2bf(f0.z); a[3]=(short)f2bf(f0.w);
      a[4]=(short)f2bf(f1.x); a[5]=(short)f2bf(f1.y); a[6]=(short)f2bf(f1.z); a[7]=(short)f2bf(f1.w);
      aq[m][st] = a;
    }
  }
  float mrow[2][4], lrow[2][4];
  floatx4 o[2][4];
  #pragma unroll
  for (int m = 0; m < 2; ++m) {
    #pragma unroll
    for (int i = 0; i < 4; ++i) { mrow[m][i] = -INFINITY; lrow[m][i] = 0.f; }
    #pragma unroll
    for (int f = 0; f < 4; ++f) o[m][f] = (floatx4){0.f, 0.f, 0.f, 0.f};
  }
  const float scale = 0.125f;
  for (int ch = 0; ch < SLEN / 64; ++ch) {
    const int k0 = ch * 64;
    __syncthreads();
    {
      const int c4 = (t & 15) * 4;
      const int r0 = t >> 4;
      const float* kp = Kg + ((size_t)bh * SLEN + k0 + r0) * DDIM + c4;
      #pragma unroll
      for (int r = 0; r < 4; ++r) {
        const float4 v = *(const float4*)(kp + (size_t)(16 * r) * DDIM);
        short4v bq2;
        bq2[0]=(short)f2bf(v.x); bq2[1]=(short)f2bf(v.y); bq2[2]=(short)f2bf(v.z); bq2[3]=(short)f2bf(v.w);
        *(short4v*)&K_lds[(r0 + 16 * r) * KSTR + c4] = bq2;
      }
    }
    {
      const int kb = (t >> 4) * 4;
      const int db = (t & 15) * 4;
      const float* vp = Vg + ((size_t)bh * SLEN + k0 + kb) * DDIM + db;
      const float4 r0 = *(const float4*)(vp);
      const float4 r1 = *(const float4*)(vp + DDIM);
      const float4 r2 = *(const float4*)(vp + 2 * DDIM);
      const float4 r3 = *(const float4*)(vp + 3 * DDIM);
      short4v wa, wb, wc, wd;
      wa[0]=(short)f2bf(r0.x); wa[1]=(short)f2bf(r1.x); wa[2]=(short)f2bf(r2.x); wa[3]=(short)f2bf(r3.x);
      wb[0]=(short)f2bf(r0.y); wb[1]=(short)f2bf(r1.y); wb[2]=(short)f2bf(r2.y); wb[3]=(short)f2bf(r3.y);
      wc[0]=(short)f2bf(r0.z); wc[1]=(short)f2bf(r1.z); wc[2]=(short)f2bf(r2.z); wc[3]=(short)f2bf(r3.z);
      wd[0]=(short)f2bf(r0.w); wd[1]=(short)f2bf(r1.w); wd[2]=(short)f2bf(r2.w); wd[3]=(short)f2bf(r3.w);
      *(short4v*)&VT_lds[(db + 0) * KSTR + kb] = wa;
      *(short4v*)&VT_lds[(db + 1) * KSTR + kb] = wb;
      *(short4v*)&VT_lds[(db + 2) * KSTR + kb] = wc;
      *(short4v*)&VT_lds[(db + 3) * KSTR + kb] = wd;
    }
    __syncthreads();
    floatx4 c[2][4];
    #pragma unroll
    for (int m = 0; m < 2; ++m)
      #pragma unroll
      for (int f = 0; f < 4; ++f) c[m][f] = (floatx4){0.f, 0.f, 0.f, 0.f};
    #pragma unroll
    for (int f = 0; f < 4; ++f) {
      const short8v b0 = *(const short8v*)&K_lds[(16 * f + ln) * KSTR + g * 8];
      const short8v b1 = *(const short8v*)&K_lds[(16 * f + ln) * KSTR + 32 + g * 8];
      #pragma unroll
      for (int m = 0; m < 2; ++m) {
        c[m][f] = __builtin_amdgcn_mfma_f32_16x16x32_bf16(aq[m][0], b0, c[m][f], 0, 0, 0);
        c[m][f] = __builtin_amdgcn_mfma_f32_16x16x32_bf16(aq[m][1], b1, c[m][f], 0, 0, 0);
      }
    }
    #pragma unroll
    for (int m = 0; m < 2; ++m) {
      float s[4][4];
      #pragma unroll
      for (int f = 0; f < 4; ++f) {
        const int kgl = k0 + 16 * f + ln;
        const bool valid = kgl < vl;
        #pragma unroll
        for (int i = 0; i < 4; ++i)
          s[f][i] = valid ? c[m][f][i] * scale : 1e-6f;
      }
      #pragma unroll
      for (int i = 0; i < 4; ++i) {
        float r = fmaxf(fmaxf(s[0][i], s[1][i]), fmaxf(s[2][i], s[3][i]));
        r = fmaxf(r, __shfl_xor(r, 1));
        r = fmaxf(r, __shfl_xor(r, 2));
        r = fmaxf(r, __shfl_xor(r, 4));
        r = fmaxf(r, __shfl_xor(r, 8));
        const float mn = fmaxf(mrow[m][i], r);
        const float al = __expf(mrow[m][i] - mn);
        mrow[m][i] = mn;
        float rs = 0.f;
        #pragma unroll
        for (int f = 0; f < 4; ++f) {
          const unsigned short pb = f2bf(__expf(s[f][i] - mn));
          P_lds[w][(m * 16 + g * 4 + i) * KSTR + 16 * f + ln] = pb;
          rs += bf2f(pb);
        }
        rs += __shfl_xor(rs, 1);
        rs += __shfl_xor(rs, 2);
        rs += __shfl_xor(rs, 4);
        rs += __shfl_xor(rs, 8);
        lrow[m][i] = lrow[m][i] * al + rs;
        #pragma unroll
        for (int f = 0; f < 4; ++f) o[m][f][i] *= al;
      }
    }
    #pragma unroll
    for (int st = 0; st < 2; ++st) {
      const short8v ap0 = *(const short8v*)&P_lds[w][(ln)*KSTR + st * 32 + g * 8];
      const short8v ap1 = *(const short8v*)&P_lds[w][(16 + ln) * KSTR + st * 32 + g * 8];
      #pragma unroll
      for (int f = 0; f < 4; ++f) {
        const short8v bv = *(const short8v*)&VT_lds[(16 * f + ln) * KSTR + st * 32 + g * 8];
        o[0][f] = __builtin_amdgcn_mfma_f32_16x16x32_bf16(ap0, bv, o[0][f], 0, 0, 0);
        o[1][f] = __builtin_amdgcn_mfma_f32_16x16x32_bf16(ap1, bv, o[1][f], 0, 0, 0);
      }
    }
  }
  #pragma unroll
  for (int m = 0; m < 2; ++m) {
    float inv[4];
    #pragma unroll
    for (int i = 0; i < 4; ++i) inv[i] = 1.0f / lrow[m][i];
    #pragma unroll
    for (int f = 0; f < 4; ++f) {
      #pragma unroll
      for (int i = 0; i < 4; ++i) {
        const size_t row = (size_t)bh * SLEN + q0 + w * 32 + m * 16 + g * 4 + i;
        Og[row * DDIM + 16 * f + ln] = o[m][f][i] * inv[i];
      }
    }
  }
}

extern "C" void kernel_launch(void* const* d_in, const int* in_sizes, int n_in,
                              void* d_out, int out_size, void* d_ws, size_t ws_size,
                              hipStream_t stream) {
  const float* Q = (const float*)d_in[0];
  const float* K = (const float*)d_in[1];
  const float* V = (const float*)d_in[2];
  const int*  vl = (const int*)d_in[3];
  float* out = (float*)d_out;

  const size_t ws_kv = (size_t)2 * NBH * SLEN * DDIM * 2;      // 33,554,432 B (K+V bf16)
  const size_t ws_sv = ws_kv + (size_t)NBH * 16 * 64 * 4;      // +524,288 B (suffix sums)

  if (ws_size >= ws_kv) {
    unsigned short* wsK  = (unsigned short*)d_ws;
    unsigned short* wsVT = wsK + (size_t)NBH * SLEN * DDIM;
    float* CS = (ws_size >= ws_sv) ? (float*)((char*)d_ws + ws_kv) : nullptr;
    prep_k<<<4096, 256, 0, stream>>>(K, wsK);
    prep_v<<<512, 256, 0, stream>>>(V, wsVT, CS);
    if (CS) prep_sv<<<NBH, 64, 0, stream>>>(CS);
    attn_main<<<dim3(SLEN / 128, NBH), dim3(256), 0, stream>>>(Q, wsK, wsVT, CS, vl, out);
  } else {
    attn_fwd_fallback<<<dim3(SLEN / 128, NBH), dim3(256), 0, stream>>>(Q, K, V, vl, out);
  }
}